// Round 2
// baseline (855.103 us; speedup 1.0000x reference)
//
#include <hip/hip_runtime.h>

typedef unsigned short ushort_t;
typedef short bf16x8 __attribute__((ext_vector_type(8)));
typedef float f32x4 __attribute__((ext_vector_type(4)));

#define B_ 64
#define H_ 512
#define E_ 300
#define V_ 50257
#define S_ 128

// output element offsets (element-indexed, dtype-agnostic)
#define PRED_OFS 0
#define HNEW_OFS ((size_t)64 * 50257)
#define A_OFS    ((size_t)64 * 50257 + 64 * 512)

__device__ __forceinline__ float b2f(unsigned short h) {
  unsigned int u = ((unsigned int)h) << 16;
  return __builtin_bit_cast(float, u);
}
__device__ __forceinline__ unsigned short f2b(float f) {
  unsigned int u = __builtin_bit_cast(unsigned int, f);
  u = u + 0x7FFFu + ((u >> 16) & 1u);
  return (unsigned short)(u >> 16);
}
__device__ __forceinline__ float fast_tanh(float x) {
  x = fminf(15.f, fmaxf(-15.f, x));
  float e = __expf(-2.f * x);
  return (1.f - e) / (1.f + e);
}
__device__ __forceinline__ float fast_sigmoid(float x) {
  return 1.f / (1.f + __expf(-x));
}

// DT: 0 = bf16 buffer, 1 = f32 buffer. Returns 4 consecutive elems as bf16x4.
template <int DT>
__device__ __forceinline__ ushort4 ldb4(const void* p, size_t off) {
  if constexpr (DT == 0) {
    return *(const ushort4*)((const ushort_t*)p + off);
  } else {
    float4 f = *(const float4*)((const float*)p + off);
    return make_ushort4(f2b(f.x), f2b(f.y), f2b(f.z), f2b(f.w));
  }
}
template <int DT>
__device__ __forceinline__ float lde1(const void* p, size_t off) {
  if constexpr (DT == 0) return b2f(((const ushort_t*)p)[off]);
  else return ((const float*)p)[off];
}
template <int DT>
__device__ __forceinline__ void st1(void* p, size_t off, float v) {
  if constexpr (DT == 0) ((ushort_t*)p)[off] = f2b(v);
  else ((float*)p)[off] = v;
}

// ---------------------------------------------------------------------------
// Dtype detector: true-bf16 N(0,1) data never has bf16 exponent >= 0xC8;
// f32 data viewed as ushorts has ~22% of even halves there.
// ---------------------------------------------------------------------------
__global__ void detect_dtype(const ushort_t* __restrict__ hidden, int* __restrict__ dtf) {
  __shared__ int cnt;
  if (threadIdx.x == 0) cnt = 0;
  __syncthreads();
  int local = 0;
  for (int i = threadIdx.x; i < 32768; i += 256) {
    unsigned e = (hidden[i] >> 7) & 0xFFu;
    if (e >= 0xC8u) local++;
  }
  atomicAdd(&cnt, local);
  __syncthreads();
  if (threadIdx.x == 0) dtf[0] = (cnt > 50) ? 1 : 0;
}

// ---------------------------------------------------------------------------
// Generic GEMM: C[M,N](f32) = A[M,K]@W[N,K]^T + bias. 64x64 tile, 4 waves.
// DTA/DTW = dtypes of A and W/bias buffers. Runs only when *dtf == want.
// ---------------------------------------------------------------------------
template <int DTA, int DTW>
__global__ __launch_bounds__(256) void gemm_tile(
    const int* __restrict__ dtf, int want,
    const void* __restrict__ A, int lda,
    const void* __restrict__ W, int ldw, int wofs,
    const void* __restrict__ bias,
    float* __restrict__ C, int ldc,
    int M, int N, int K)
{
  if (dtf[0] != want) return;
  __shared__ ushort_t sA[64 * 40];
  __shared__ ushort_t sB[64 * 40];
  const int tid = threadIdx.x;
  const int n0 = blockIdx.x * 64, m0 = blockIdx.y * 64;
  const int wave = tid >> 6, lane = tid & 63, quad = lane >> 4, l16 = lane & 15;

  f32x4 acc[4];
  #pragma unroll
  for (int i = 0; i < 4; ++i) acc[i] = (f32x4){0.f, 0.f, 0.f, 0.f};

  const int ksteps = (K + 31) >> 5;
  for (int kt = 0; kt < ksteps; ++kt) {
    #pragma unroll
    for (int i = 0; i < 2; ++i) {
      int g = tid + i * 256;            // 0..511
      int row = g >> 3, gc = (g & 7) << 2;
      int gk = kt * 32 + gc;
      int ar = m0 + row, wr = n0 + row;
      ushort4 va = make_ushort4(0, 0, 0, 0);
      ushort4 vb = make_ushort4(0, 0, 0, 0);
      if (gk < K && ar < M) va = ldb4<DTA>(A, (size_t)ar * lda + gk);
      if (gk < K && wr < N) vb = ldb4<DTW>(W, (size_t)wr * ldw + wofs + gk);
      *(ushort4*)(sA + row * 40 + gc) = va;
      *(ushort4*)(sB + row * 40 + gc) = vb;
    }
    __syncthreads();
    bf16x8 af = *(const bf16x8*)(sA + (wave * 16 + l16) * 40 + quad * 8);
    #pragma unroll
    for (int nt = 0; nt < 4; ++nt) {
      bf16x8 bfr = *(const bf16x8*)(sB + (nt * 16 + l16) * 40 + quad * 8);
      acc[nt] = __builtin_amdgcn_mfma_f32_16x16x32_bf16(af, bfr, acc[nt], 0, 0, 0);
    }
    __syncthreads();
  }
  #pragma unroll
  for (int nt = 0; nt < 4; ++nt) {
    #pragma unroll
    for (int reg = 0; reg < 4; ++reg) {
      int row = m0 + wave * 16 + quad * 4 + reg;
      int col = n0 + nt * 16 + l16;
      if (row < M && col < N)
        C[(size_t)row * ldc + col] = acc[nt][reg] + lde1<DTW>(bias, col);
    }
  }
}

// ---------------------------------------------------------------------------
// Attention scores: r = s*64+b; scores[r] += sum_h v[h]*tanh(enc@Wa^T + Gh).
// ---------------------------------------------------------------------------
template <int DT>
__global__ __launch_bounds__(256) void attn_scores(
    const int* __restrict__ dtf,
    const void* __restrict__ enc,     // [8192, 1024]
    const void* __restrict__ Wattn,   // [512, 1536]
    const float* __restrict__ Gh,     // [64, 512]
    const void* __restrict__ vw,      // [512]
    float* __restrict__ scores)       // [8192] zero-init
{
  if (dtf[0] != DT) return;
  __shared__ ushort_t sA[64 * 40];
  __shared__ ushort_t sB[64 * 40];
  const int tid = threadIdx.x;
  const int n0 = blockIdx.x * 64, m0 = blockIdx.y * 64;
  const int wave = tid >> 6, lane = tid & 63, quad = lane >> 4, l16 = lane & 15;

  f32x4 acc[4];
  #pragma unroll
  for (int i = 0; i < 4; ++i) acc[i] = (f32x4){0.f, 0.f, 0.f, 0.f};

  for (int kt = 0; kt < 32; ++kt) {      // K=1024
    #pragma unroll
    for (int i = 0; i < 2; ++i) {
      int g = tid + i * 256;
      int row = g >> 3, gc = (g & 7) << 2;
      int gk = kt * 32 + gc;
      ushort4 va = ldb4<DT>(enc, (size_t)(m0 + row) * 1024 + gk);
      ushort4 vb = ldb4<DT>(Wattn, (size_t)(n0 + row) * 1536 + 512 + gk);
      *(ushort4*)(sA + row * 40 + gc) = va;
      *(ushort4*)(sB + row * 40 + gc) = vb;
    }
    __syncthreads();
    bf16x8 af = *(const bf16x8*)(sA + (wave * 16 + l16) * 40 + quad * 8);
    #pragma unroll
    for (int nt = 0; nt < 4; ++nt) {
      bf16x8 bfr = *(const bf16x8*)(sB + (nt * 16 + l16) * 40 + quad * 8);
      acc[nt] = __builtin_amdgcn_mfma_f32_16x16x32_bf16(af, bfr, acc[nt], 0, 0, 0);
    }
    __syncthreads();
  }
  float psum[4] = {0.f, 0.f, 0.f, 0.f};
  #pragma unroll
  for (int nt = 0; nt < 4; ++nt) {
    int h = n0 + nt * 16 + l16;
    float vh = lde1<DT>(vw, h);
    #pragma unroll
    for (int reg = 0; reg < 4; ++reg) {
      int r = m0 + wave * 16 + quad * 4 + reg;
      int b = r & 63;
      float e = acc[nt][reg] + Gh[b * 512 + h];
      psum[reg] += vh * fast_tanh(e);
    }
  }
  #pragma unroll
  for (int reg = 0; reg < 4; ++reg) {
    float p = psum[reg];
    p += __shfl_xor(p, 1);
    p += __shfl_xor(p, 2);
    p += __shfl_xor(p, 4);
    p += __shfl_xor(p, 8);
    if (l16 == 0) {
      int r = m0 + wave * 16 + quad * 4 + reg;
      atomicAdd(&scores[r], p);
    }
  }
}

// ---------------------------------------------------------------------------
// Per-batch: mask+softmax -> a ; context ; build x (GRU in) and xo (out-proj in).
// ---------------------------------------------------------------------------
template <int DT>
__global__ __launch_bounds__(256) void softmax_ctx(
    const int* __restrict__ dtf,
    const float* __restrict__ scores,   // [8192], index s*64+b
    const int* __restrict__ mask,       // [64, 128]
    const void* __restrict__ enc,       // [128, 64, 1024]
    const void* __restrict__ emb,       // [50257, 300]
    const int* __restrict__ ids,        // [64]
    void* __restrict__ out,             // a at A_OFS
    ushort_t* __restrict__ x,           // [64, 1344]: [emb 0:300 | w 300:1324 | pad]
    ushort_t* __restrict__ xo)          // [64, 1856]: [h 0:512 | w 512:1536 | emb 1536:1836 | pad]
{
  if (dtf[0] != DT) return;
  __shared__ float sc[128];
  __shared__ float red[128];
  const int b = blockIdx.x;
  const int tid = threadIdx.x;

  if (tid < 128) {
    float s = scores[tid * 64 + b];
    if (mask[b * 128 + tid] == 0) s = -1e10f;
    sc[tid] = s;
    red[tid] = s;
  }
  __syncthreads();
  for (int off = 64; off > 0; off >>= 1) {
    if (tid < off) red[tid] = fmaxf(red[tid], red[tid + off]);
    __syncthreads();
  }
  float m = red[0];
  __syncthreads();
  if (tid < 128) {
    float e = __expf(sc[tid] - m);
    sc[tid] = e;
    red[tid] = e;
  }
  __syncthreads();
  for (int off = 64; off > 0; off >>= 1) {
    if (tid < off) red[tid] += red[tid + off];
    __syncthreads();
  }
  float inv = 1.f / red[0];
  if (tid < 128) {
    float av = sc[tid] * inv;
    sc[tid] = av;
    st1<DT>(out, A_OFS + b * 128 + tid, av);
  }
  __syncthreads();

  // weighted context over 1024 dims (tid*4)
  {
    int e0 = tid * 4;
    float a0 = 0.f, a1 = 0.f, a2 = 0.f, a3 = 0.f;
    for (int s = 0; s < 128; ++s) {
      float as = sc[s];
      ushort4 ev = ldb4<DT>(enc, (size_t)(s * 64 + b) * 1024 + e0);
      a0 += as * b2f(ev.x);
      a1 += as * b2f(ev.y);
      a2 += as * b2f(ev.z);
      a3 += as * b2f(ev.w);
    }
    ushort4 wb = make_ushort4(f2b(a0), f2b(a1), f2b(a2), f2b(a3));
    *(ushort4*)(x + b * 1344 + 300 + e0) = wb;
    *(ushort4*)(xo + b * 1856 + 512 + e0) = wb;
  }

  // embedding gather
  int rid = ids[b];
  for (int e = tid; e < 300; e += 256) {
    ushort_t h = f2b(lde1<DT>(emb, (size_t)rid * 300 + e));
    x[b * 1344 + e] = h;
    xo[b * 1856 + 1536 + e] = h;
  }
  // zero pads
  if (tid < 20) {
    x[b * 1344 + 1324 + tid] = 0;
    xo[b * 1856 + 1836 + tid] = 0;
  }
}

// ---------------------------------------------------------------------------
// GRU pointwise: r,z,n -> h_new (to out + xo[:,0:512])
// ---------------------------------------------------------------------------
template <int DT>
__global__ __launch_bounds__(256) void gru_pointwise(
    const int* __restrict__ dtf,
    const float* __restrict__ gx,       // [64, 1536]
    const float* __restrict__ gh,       // [64, 1536]
    const void* __restrict__ hidden,    // [64, 512]
    void* __restrict__ out,             // h_new at HNEW_OFS
    ushort_t* __restrict__ xo)          // [64, 1856]
{
  if (dtf[0] != DT) return;
  int i = blockIdx.x * 256 + threadIdx.x;   // 0..32767
  int b = i >> 9, h = i & 511;
  float r = fast_sigmoid(gx[b * 1536 + h] + gh[b * 1536 + h]);
  float z = fast_sigmoid(gx[b * 1536 + 512 + h] + gh[b * 1536 + 512 + h]);
  float n = fast_tanh(gx[b * 1536 + 1024 + h] + r * gh[b * 1536 + 1024 + h]);
  float hp = lde1<DT>(hidden, b * 512 + h);
  float hn = (1.f - z) * n + z * hp;
  st1<DT>(out, HNEW_OFS + b * 512 + h, hn);
  xo[b * 1856 + h] = f2b(hn);
}

// ---------------------------------------------------------------------------
// Output projection: pred[64, 50257] = xo[64,1836] @ W_out[50257,1836]^T + b_out
// ---------------------------------------------------------------------------
template <int DT>
__global__ __launch_bounds__(256) void out_proj(
    const int* __restrict__ dtf,
    const ushort_t* __restrict__ Xo,     // [64, 1856] (cols 1836.. zero)
    const void* __restrict__ Wout,       // [50257, 1836]
    const void* __restrict__ bout,       // [50257]
    void* __restrict__ out)              // pred at 0
{
  if (dtf[0] != DT) return;
  __shared__ ushort_t sA[64 * 40];
  __shared__ ushort_t sB[64 * 40];
  const int tid = threadIdx.x;
  const int n0 = blockIdx.x * 64;
  const int wave = tid >> 6, lane = tid & 63, quad = lane >> 4, l16 = lane & 15;

  f32x4 acc[4];
  #pragma unroll
  for (int i = 0; i < 4; ++i) acc[i] = (f32x4){0.f, 0.f, 0.f, 0.f};

  for (int kt = 0; kt < 58; ++kt) {     // K=1836 padded to 1856
    #pragma unroll
    for (int i = 0; i < 2; ++i) {
      int g = tid + i * 256;
      int row = g >> 3, gc = (g & 7) << 2;
      int gk = kt * 32 + gc;
      ushort4 va = make_ushort4(0, 0, 0, 0);
      ushort4 vb = make_ushort4(0, 0, 0, 0);
      if (gk < 1836) {
        va = *(const ushort4*)(Xo + (size_t)row * 1856 + gk);
        int wr = n0 + row;
        if (wr < V_) vb = ldb4<DT>(Wout, (size_t)wr * 1836 + gk);
      }
      *(ushort4*)(sA + row * 40 + gc) = va;
      *(ushort4*)(sB + row * 40 + gc) = vb;
    }
    __syncthreads();
    bf16x8 af = *(const bf16x8*)(sA + (wave * 16 + l16) * 40 + quad * 8);
    #pragma unroll
    for (int nt = 0; nt < 4; ++nt) {
      bf16x8 bfr = *(const bf16x8*)(sB + (nt * 16 + l16) * 40 + quad * 8);
      acc[nt] = __builtin_amdgcn_mfma_f32_16x16x32_bf16(af, bfr, acc[nt], 0, 0, 0);
    }
    __syncthreads();
  }
  #pragma unroll
  for (int nt = 0; nt < 4; ++nt) {
    #pragma unroll
    for (int reg = 0; reg < 4; ++reg) {
      int row = wave * 16 + quad * 4 + reg;
      int col = n0 + nt * 16 + l16;
      if (col < V_)
        st1<DT>(out, (size_t)row * V_ + col, acc[nt][reg] + lde1<DT>(bout, col));
    }
  }
}

// ---------------------------------------------------------------------------
extern "C" void kernel_launch(void* const* d_in, const int* in_sizes, int n_in,
                              void* d_out, int out_size, void* d_ws, size_t ws_size,
                              hipStream_t stream) {
  const int*  ids    = (const int*)d_in[0];
  const void* hidden = d_in[1];
  const void* enc    = d_in[2];
  const int*  mask   = (const int*)d_in[3];
  const void* emb    = d_in[4];
  const void* Wattn  = d_in[5];
  const void* battn  = d_in[6];
  const void* vw     = d_in[7];
  const void* Wih    = d_in[8];
  const void* Whh    = d_in[9];
  const void* bih    = d_in[10];
  const void* bhh    = d_in[11];
  const void* Wout   = d_in[12];
  const void* bout   = d_in[13];

  char* ws = (char*)d_ws;
  float*    scores = (float*)(ws + 0);            //  32 KB
  float*    Gh     = (float*)(ws + 32768);        //  128 KB
  float*    gx     = (float*)(ws + 425984);       //  384 KB
  float*    gh     = (float*)(ws + 819200);       //  384 KB
  ushort_t* x      = (ushort_t*)(ws + 1212416);   //  168 KB
  ushort_t* xo     = (ushort_t*)(ws + 1384448);   //  232 KB (ends 1622016)
  int*      dtf    = (int*)(ws + 1703936);

  detect_dtype<<<1, 256, 0, stream>>>((const ushort_t*)hidden, dtf);
  hipMemsetAsync(scores, 0, 8192 * sizeof(float), stream);

  // Gh = hidden @ Wattn[:, 0:512]^T + b_attn
  gemm_tile<0, 0><<<dim3(8, 1), 256, 0, stream>>>(dtf, 0, hidden, 512, Wattn, 1536, 0, battn, Gh, 512, 64, 512, 512);
  gemm_tile<1, 1><<<dim3(8, 1), 256, 0, stream>>>(dtf, 1, hidden, 512, Wattn, 1536, 0, battn, Gh, 512, 64, 512, 512);

  // scores (fused energy GEMM + tanh + v-dot)
  attn_scores<0><<<dim3(8, 128), 256, 0, stream>>>(dtf, enc, Wattn, Gh, vw, scores);
  attn_scores<1><<<dim3(8, 128), 256, 0, stream>>>(dtf, enc, Wattn, Gh, vw, scores);

  // softmax + context + build x, xo (+ a output)
  softmax_ctx<0><<<64, 256, 0, stream>>>(dtf, scores, mask, enc, emb, ids, d_out, x, xo);
  softmax_ctx<1><<<64, 256, 0, stream>>>(dtf, scores, mask, enc, emb, ids, d_out, x, xo);

  // gx = x @ W_ih^T + b_ih ; gh = hidden @ W_hh^T + b_hh
  gemm_tile<0, 0><<<dim3(24, 1), 256, 0, stream>>>(dtf, 0, x, 1344, Wih, 1324, 0, bih, gx, 1536, 64, 1536, 1324);
  gemm_tile<0, 1><<<dim3(24, 1), 256, 0, stream>>>(dtf, 1, x, 1344, Wih, 1324, 0, bih, gx, 1536, 64, 1536, 1324);
  gemm_tile<0, 0><<<dim3(24, 1), 256, 0, stream>>>(dtf, 0, hidden, 512, Whh, 512, 0, bhh, gh, 1536, 64, 1536, 512);
  gemm_tile<1, 1><<<dim3(24, 1), 256, 0, stream>>>(dtf, 1, hidden, 512, Whh, 512, 0, bhh, gh, 1536, 64, 1536, 512);

  // GRU pointwise -> h_new
  gru_pointwise<0><<<128, 256, 0, stream>>>(dtf, gx, gh, hidden, d_out, xo);
  gru_pointwise<1><<<128, 256, 0, stream>>>(dtf, gx, gh, hidden, d_out, xo);

  // prediction = xo @ W_out^T + b_out
  out_proj<0><<<786, 256, 0, stream>>>(dtf, xo, Wout, bout, d_out);
  out_proj<1><<<786, 256, 0, stream>>>(dtf, xo, Wout, bout, d_out);
}

// Round 3
// 719.591 us; speedup vs baseline: 1.1883x; 1.1883x over previous
//
#include <hip/hip_runtime.h>

typedef unsigned short ushort_t;
typedef short bf16x8 __attribute__((ext_vector_type(8)));
typedef float f32x4 __attribute__((ext_vector_type(4)));

#define B_ 64
#define H_ 512
#define E_ 300
#define V_ 50257
#define S_ 128

// output element offsets (f32 elements)
#define HNEW_OFS ((size_t)64 * 50257)
#define A_OFS    ((size_t)64 * 50257 + 64 * 512)

__device__ __forceinline__ unsigned short f2b(float f) {
  unsigned int u = __builtin_bit_cast(unsigned int, f);
  u = u + 0x7FFFu + ((u >> 16) & 1u);
  return (unsigned short)(u >> 16);
}
__device__ __forceinline__ float fast_tanh(float x) {
  x = fminf(15.f, fmaxf(-15.f, x));
  float e = __expf(-2.f * x);
  return (1.f - e) / (1.f + e);
}
__device__ __forceinline__ float fast_sigmoid(float x) {
  return 1.f / (1.f + __expf(-x));
}

// Raw 4-element load (DT: 0=bf16 buffer, 1=f32 buffer), converted to bf16x4
// only at LDS-write time so the load's vmcnt wait lands in the next k-step.
template <int DT> struct Raw4;
template <> struct Raw4<0> {
  ushort4 v;
  __device__ static Raw4 zero() { return {make_ushort4(0, 0, 0, 0)}; }
};
template <> struct Raw4<1> {
  float4 v;
  __device__ static Raw4 zero() { return {make_float4(0.f, 0.f, 0.f, 0.f)}; }
};
template <int DT>
__device__ __forceinline__ Raw4<DT> ld_raw(const void* p, size_t off);
template <>
__device__ __forceinline__ Raw4<0> ld_raw<0>(const void* p, size_t off) {
  return {*(const ushort4*)((const ushort_t*)p + off)};
}
template <>
__device__ __forceinline__ Raw4<1> ld_raw<1>(const void* p, size_t off) {
  return {*(const float4*)((const float*)p + off)};
}
template <int DT>
__device__ __forceinline__ ushort4 to_b4(Raw4<DT> r);
template <>
__device__ __forceinline__ ushort4 to_b4<0>(Raw4<0> r) { return r.v; }
template <>
__device__ __forceinline__ ushort4 to_b4<1>(Raw4<1> r) {
  return make_ushort4(f2b(r.v.x), f2b(r.v.y), f2b(r.v.z), f2b(r.v.w));
}

// ---------------------------------------------------------------------------
// Generic GEMM: C[M,N](f32) = A[M,K] @ W[N,K]^T + bias. 64x64 tile, 4 waves,
// register-prefetch pipelined staging.
// ---------------------------------------------------------------------------
template <int DTA, int DTW>
__global__ __launch_bounds__(256) void gemm_tile(
    const void* __restrict__ A, int lda,
    const void* __restrict__ W, int ldw, int wofs,
    const float* __restrict__ bias,
    float* __restrict__ C, int ldc,
    int M, int N, int K)
{
  __shared__ ushort_t sA[64 * 40];
  __shared__ ushort_t sB[64 * 40];
  const int tid = threadIdx.x;
  const int n0 = blockIdx.x * 64, m0 = blockIdx.y * 64;
  const int wave = tid >> 6, lane = tid & 63, quad = lane >> 4, l16 = lane & 15;

  f32x4 acc[4];
  #pragma unroll
  for (int i = 0; i < 4; ++i) acc[i] = (f32x4){0.f, 0.f, 0.f, 0.f};

  Raw4<DTA> ra[2];
  Raw4<DTW> rb[2];
  auto fetch = [&](int kt) {
    #pragma unroll
    for (int i = 0; i < 2; ++i) {
      int g = tid + i * 256;
      int row = g >> 3, gc = (g & 7) << 2;
      int gk = kt * 32 + gc;
      int ar = m0 + row, wr = n0 + row;
      ra[i] = Raw4<DTA>::zero();
      rb[i] = Raw4<DTW>::zero();
      if (gk < K && ar < M) ra[i] = ld_raw<DTA>(A, (size_t)ar * lda + gk);
      if (gk < K && wr < N) rb[i] = ld_raw<DTW>(W, (size_t)wr * ldw + wofs + gk);
    }
  };
  const int ksteps = (K + 31) >> 5;
  fetch(0);
  for (int kt = 0; kt < ksteps; ++kt) {
    #pragma unroll
    for (int i = 0; i < 2; ++i) {
      int g = tid + i * 256;
      int row = g >> 3, gc = (g & 7) << 2;
      *(ushort4*)(sA + row * 40 + gc) = to_b4<DTA>(ra[i]);
      *(ushort4*)(sB + row * 40 + gc) = to_b4<DTW>(rb[i]);
    }
    __syncthreads();
    if (kt + 1 < ksteps) fetch(kt + 1);
    bf16x8 af = *(const bf16x8*)(sA + (wave * 16 + l16) * 40 + quad * 8);
    #pragma unroll
    for (int nt = 0; nt < 4; ++nt) {
      bf16x8 bfr = *(const bf16x8*)(sB + (nt * 16 + l16) * 40 + quad * 8);
      acc[nt] = __builtin_amdgcn_mfma_f32_16x16x32_bf16(af, bfr, acc[nt], 0, 0, 0);
    }
    __syncthreads();
  }
  #pragma unroll
  for (int nt = 0; nt < 4; ++nt) {
    #pragma unroll
    for (int reg = 0; reg < 4; ++reg) {
      int row = m0 + wave * 16 + quad * 4 + reg;
      int col = n0 + nt * 16 + l16;
      if (row < M && col < N)
        C[(size_t)row * ldc + col] = acc[nt][reg] + bias[col];
    }
  }
}

// ---------------------------------------------------------------------------
// Attention scores, partial per n-block (no atomics, no init needed):
// scores_part[nb][r] = sum_{h in nb-tile} v[h]*tanh(enc[r]@Wa[h]^T + Gh[b][h])
// ---------------------------------------------------------------------------
__global__ __launch_bounds__(256) void attn_scores(
    const float* __restrict__ enc,     // [8192, 1024]
    const float* __restrict__ Wattn,   // [512, 1536]
    const float* __restrict__ Gh,      // [64, 512]
    const float* __restrict__ vw,      // [512]
    float* __restrict__ scores_part)   // [8, 8192]
{
  __shared__ ushort_t sA[64 * 40];
  __shared__ ushort_t sB[64 * 40];
  const int tid = threadIdx.x;
  const int n0 = blockIdx.x * 64, m0 = blockIdx.y * 64;
  const int wave = tid >> 6, lane = tid & 63, quad = lane >> 4, l16 = lane & 15;

  f32x4 acc[4];
  #pragma unroll
  for (int i = 0; i < 4; ++i) acc[i] = (f32x4){0.f, 0.f, 0.f, 0.f};

  float4 ra[2], rb[2];
  auto fetch = [&](int kt) {
    #pragma unroll
    for (int i = 0; i < 2; ++i) {
      int g = tid + i * 256;
      int row = g >> 3, gc = (g & 7) << 2;
      int gk = kt * 32 + gc;
      ra[i] = *(const float4*)(enc + (size_t)(m0 + row) * 1024 + gk);
      rb[i] = *(const float4*)(Wattn + (size_t)(n0 + row) * 1536 + 512 + gk);
    }
  };
  fetch(0);
  for (int kt = 0; kt < 32; ++kt) {      // K=1024
    #pragma unroll
    for (int i = 0; i < 2; ++i) {
      int g = tid + i * 256;
      int row = g >> 3, gc = (g & 7) << 2;
      *(ushort4*)(sA + row * 40 + gc) =
          make_ushort4(f2b(ra[i].x), f2b(ra[i].y), f2b(ra[i].z), f2b(ra[i].w));
      *(ushort4*)(sB + row * 40 + gc) =
          make_ushort4(f2b(rb[i].x), f2b(rb[i].y), f2b(rb[i].z), f2b(rb[i].w));
    }
    __syncthreads();
    if (kt + 1 < 32) fetch(kt + 1);
    bf16x8 af = *(const bf16x8*)(sA + (wave * 16 + l16) * 40 + quad * 8);
    #pragma unroll
    for (int nt = 0; nt < 4; ++nt) {
      bf16x8 bfr = *(const bf16x8*)(sB + (nt * 16 + l16) * 40 + quad * 8);
      acc[nt] = __builtin_amdgcn_mfma_f32_16x16x32_bf16(af, bfr, acc[nt], 0, 0, 0);
    }
    __syncthreads();
  }
  float psum[4] = {0.f, 0.f, 0.f, 0.f};
  #pragma unroll
  for (int nt = 0; nt < 4; ++nt) {
    int h = n0 + nt * 16 + l16;
    float vh = vw[h];
    #pragma unroll
    for (int reg = 0; reg < 4; ++reg) {
      int r = m0 + wave * 16 + quad * 4 + reg;
      int b = r & 63;
      float e = acc[nt][reg] + Gh[b * 512 + h];
      psum[reg] += vh * fast_tanh(e);
    }
  }
  #pragma unroll
  for (int reg = 0; reg < 4; ++reg) {
    float p = psum[reg];
    p += __shfl_xor(p, 1);
    p += __shfl_xor(p, 2);
    p += __shfl_xor(p, 4);
    p += __shfl_xor(p, 8);
    if (l16 == 0) {
      int r = m0 + wave * 16 + quad * 4 + reg;
      scores_part[blockIdx.x * 8192 + r] = p;
    }
  }
}

// ---------------------------------------------------------------------------
// Per-batch: sum partials + mask + softmax -> a ; context ; build x and xo.
// ---------------------------------------------------------------------------
__global__ __launch_bounds__(256) void softmax_ctx(
    const float* __restrict__ scores_part, // [8, 8192], index nb*8192 + s*64+b
    const int* __restrict__ mask,       // [64, 128]
    const float* __restrict__ enc,      // [128, 64, 1024]
    const float* __restrict__ emb,      // [50257, 300]
    const int* __restrict__ ids,        // [64]
    float* __restrict__ out,            // a at A_OFS
    ushort_t* __restrict__ x,           // [64, 1344]: [emb 0:300 | w 300:1324 | pad]
    ushort_t* __restrict__ xo)          // [64, 1856]: [h 0:512 | w 512:1536 | emb 1536:1836 | pad]
{
  __shared__ float sc[128];
  __shared__ float red[128];
  const int b = blockIdx.x;
  const int tid = threadIdx.x;

  if (tid < 128) {
    float s = 0.f;
    #pragma unroll
    for (int nb = 0; nb < 8; ++nb) s += scores_part[nb * 8192 + tid * 64 + b];
    if (mask[b * 128 + tid] == 0) s = -1e10f;
    sc[tid] = s;
    red[tid] = s;
  }
  __syncthreads();
  for (int off = 64; off > 0; off >>= 1) {
    if (tid < off) red[tid] = fmaxf(red[tid], red[tid + off]);
    __syncthreads();
  }
  float m = red[0];
  __syncthreads();
  if (tid < 128) {
    float e = __expf(sc[tid] - m);
    sc[tid] = e;
    red[tid] = e;
  }
  __syncthreads();
  for (int off = 64; off > 0; off >>= 1) {
    if (tid < off) red[tid] += red[tid + off];
    __syncthreads();
  }
  float inv = 1.f / red[0];
  if (tid < 128) {
    float av = sc[tid] * inv;
    sc[tid] = av;
    out[A_OFS + b * 128 + tid] = av;
  }
  __syncthreads();

  // weighted context over 1024 dims (tid*4)
  {
    int e0 = tid * 4;
    float a0 = 0.f, a1 = 0.f, a2 = 0.f, a3 = 0.f;
    for (int s = 0; s < 128; ++s) {
      float as = sc[s];
      float4 ev = *(const float4*)(enc + (size_t)(s * 64 + b) * 1024 + e0);
      a0 += as * ev.x;
      a1 += as * ev.y;
      a2 += as * ev.z;
      a3 += as * ev.w;
    }
    ushort4 wb = make_ushort4(f2b(a0), f2b(a1), f2b(a2), f2b(a3));
    *(ushort4*)(x + b * 1344 + 300 + e0) = wb;
    *(ushort4*)(xo + b * 1856 + 512 + e0) = wb;
  }

  // embedding gather
  int rid = ids[b];
  for (int e = tid; e < 300; e += 256) {
    ushort_t h = f2b(emb[(size_t)rid * 300 + e]);
    x[b * 1344 + e] = h;
    xo[b * 1856 + 1536 + e] = h;
  }
  // zero pads
  if (tid < 20) {
    x[b * 1344 + 1324 + tid] = 0;
    xo[b * 1856 + 1836 + tid] = 0;
  }
}

// ---------------------------------------------------------------------------
// GRU pointwise: r,z,n -> h_new (to out + xo[:,0:512])
// ---------------------------------------------------------------------------
__global__ __launch_bounds__(256) void gru_pointwise(
    const float* __restrict__ gx,       // [64, 1536]
    const float* __restrict__ gh,       // [64, 1536]
    const float* __restrict__ hidden,   // [64, 512]
    float* __restrict__ out,            // h_new at HNEW_OFS
    ushort_t* __restrict__ xo)          // [64, 1856]
{
  int i = blockIdx.x * 256 + threadIdx.x;   // 0..32767
  int b = i >> 9, h = i & 511;
  float r = fast_sigmoid(gx[b * 1536 + h] + gh[b * 1536 + h]);
  float z = fast_sigmoid(gx[b * 1536 + 512 + h] + gh[b * 1536 + 512 + h]);
  float n = fast_tanh(gx[b * 1536 + 1024 + h] + r * gh[b * 1536 + 1024 + h]);
  float hp = hidden[b * 512 + h];
  float hn = (1.f - z) * n + z * hp;
  out[HNEW_OFS + b * 512 + h] = hn;
  xo[b * 1856 + h] = f2b(hn);
}

// ---------------------------------------------------------------------------
// Output projection: pred[64,50257] = xo[64,1836] @ W_out[50257,1836]^T + b_out
// Memory-bound (369 MB of f32 W_out). Pipelined staging.
// ---------------------------------------------------------------------------
__global__ __launch_bounds__(256) void out_proj(
    const ushort_t* __restrict__ Xo,     // [64, 1856] bf16 (cols 1836.. zero)
    const float* __restrict__ Wout,      // [50257, 1836] f32
    const float* __restrict__ bout,      // [50257]
    float* __restrict__ pred)            // [64, 50257]
{
  __shared__ ushort_t sA[64 * 40];
  __shared__ ushort_t sB[64 * 40];
  const int tid = threadIdx.x;
  const int n0 = blockIdx.x * 64;
  const int wave = tid >> 6, lane = tid & 63, quad = lane >> 4, l16 = lane & 15;

  f32x4 acc[4];
  #pragma unroll
  for (int i = 0; i < 4; ++i) acc[i] = (f32x4){0.f, 0.f, 0.f, 0.f};

  ushort4 ra[2];
  float4 rb[2];
  auto fetch = [&](int kt) {
    #pragma unroll
    for (int i = 0; i < 2; ++i) {
      int g = tid + i * 256;
      int row = g >> 3, gc = (g & 7) << 2;
      int gk = kt * 32 + gc;
      ra[i] = make_ushort4(0, 0, 0, 0);
      rb[i] = make_float4(0.f, 0.f, 0.f, 0.f);
      if (gk < 1836) {
        ra[i] = *(const ushort4*)(Xo + (size_t)row * 1856 + gk);
        int wr = n0 + row;
        if (wr < V_) rb[i] = *(const float4*)(Wout + (size_t)wr * 1836 + gk);
      }
    }
  };
  fetch(0);
  for (int kt = 0; kt < 58; ++kt) {     // K=1836 padded to 1856
    #pragma unroll
    for (int i = 0; i < 2; ++i) {
      int g = tid + i * 256;
      int row = g >> 3, gc = (g & 7) << 2;
      *(ushort4*)(sA + row * 40 + gc) = ra[i];
      *(ushort4*)(sB + row * 40 + gc) =
          make_ushort4(f2b(rb[i].x), f2b(rb[i].y), f2b(rb[i].z), f2b(rb[i].w));
    }
    __syncthreads();
    if (kt + 1 < 58) fetch(kt + 1);
    bf16x8 af = *(const bf16x8*)(sA + (wave * 16 + l16) * 40 + quad * 8);
    #pragma unroll
    for (int nt = 0; nt < 4; ++nt) {
      bf16x8 bfr = *(const bf16x8*)(sB + (nt * 16 + l16) * 40 + quad * 8);
      acc[nt] = __builtin_amdgcn_mfma_f32_16x16x32_bf16(af, bfr, acc[nt], 0, 0, 0);
    }
    __syncthreads();
  }
  #pragma unroll
  for (int nt = 0; nt < 4; ++nt) {
    #pragma unroll
    for (int reg = 0; reg < 4; ++reg) {
      int row = wave * 16 + quad * 4 + reg;
      int col = n0 + nt * 16 + l16;
      if (col < V_)
        pred[(size_t)row * V_ + col] = acc[nt][reg] + bout[col];
    }
  }
}

// ---------------------------------------------------------------------------
extern "C" void kernel_launch(void* const* d_in, const int* in_sizes, int n_in,
                              void* d_out, int out_size, void* d_ws, size_t ws_size,
                              hipStream_t stream) {
  const int*   ids    = (const int*)d_in[0];
  const float* hidden = (const float*)d_in[1];
  const float* enc    = (const float*)d_in[2];
  const int*   mask   = (const int*)d_in[3];
  const float* emb    = (const float*)d_in[4];
  const float* Wattn  = (const float*)d_in[5];
  const float* battn  = (const float*)d_in[6];
  const float* vw     = (const float*)d_in[7];
  const float* Wih    = (const float*)d_in[8];
  const float* Whh    = (const float*)d_in[9];
  const float* bih    = (const float*)d_in[10];
  const float* bhh    = (const float*)d_in[11];
  const float* Wout   = (const float*)d_in[12];
  const float* bout   = (const float*)d_in[13];
  float* out = (float*)d_out;

  char* ws = (char*)d_ws;
  float*    scores_part = (float*)(ws + 0);          // 8*8192 f32 = 256 KB
  float*    Gh          = (float*)(ws + 262144);     // 64*512 f32 = 128 KB
  float*    gx          = (float*)(ws + 393216);     // 64*1536 f32 = 384 KB
  float*    gh          = (float*)(ws + 786432);     // 64*1536 f32 = 384 KB
  ushort_t* x           = (ushort_t*)(ws + 1179648); // 64*1344 bf16 = 168 KB
  ushort_t* xo          = (ushort_t*)(ws + 1351680); // 64*1856 bf16 = 232 KB

  // Gh = hidden @ Wattn[:, 0:512]^T + b_attn
  gemm_tile<1, 1><<<dim3(8, 1), 256, 0, stream>>>(
      hidden, 512, Wattn, 1536, 0, battn, Gh, 512, 64, 512, 512);

  // partial attention scores (fused energy GEMM + tanh + v-dot)
  attn_scores<<<dim3(8, 128), 256, 0, stream>>>(enc, Wattn, Gh, vw, scores_part);

  // softmax + context + build x, xo (+ a output)
  softmax_ctx<<<64, 256, 0, stream>>>(scores_part, mask, enc, emb, ids, out, x, xo);

  // gx = x @ W_ih^T + b_ih ; gh = hidden @ W_hh^T + b_hh
  gemm_tile<0, 1><<<dim3(24, 1), 256, 0, stream>>>(
      x, 1344, Wih, 1324, 0, bih, gx, 1536, 64, 1536, 1324);
  gemm_tile<1, 1><<<dim3(24, 1), 256, 0, stream>>>(
      hidden, 512, Whh, 512, 0, bhh, gh, 1536, 64, 1536, 512);

  // GRU pointwise -> h_new
  gru_pointwise<<<128, 256, 0, stream>>>(gx, gh, hidden, out, xo);

  // prediction = xo @ W_out^T + b_out
  out_proj<<<786, 256, 0, stream>>>(xo, Wout, bout, out);
}